// Round 12
// baseline (411.001 us; speedup 1.0000x reference)
//
#include <hip/hip_runtime.h>
#include <stdint.h>

#define NROWS 8192
#define DDIM  256
#define K2    512          // hi|lo shorts per row (size bookkeeping only)
#define BLKSTRIDE 131072   // shorts per 256-row block (16 units x 8192)
#define MARGIN_F 0.2f
#define MFMA16 __builtin_amdgcn_mfma_f32_16x16x32_bf16
#define SBAR0() __builtin_amdgcn_sched_barrier(0)

typedef short  short8  __attribute__((ext_vector_type(8)));
typedef float  floatx4 __attribute__((ext_vector_type(4)));

// Unit-packed operand layout (R18, verified absmax 0): each 16KB staging unit
// (blk, kc, hl) is contiguous; slot swizzle baked in at pack time.
__device__ unsigned short gA[(size_t)NROWS * K2];   // im, unit-packed
__device__ unsigned short gB[(size_t)NROWS * K2];   // s,  unit-packed
__device__ float    g_diag[NROWS];
__device__ unsigned g_rowcnt[NROWS];
__device__ unsigned g_rowkey[NROWS];
__device__ unsigned g_colcnt[NROWS];
__device__ unsigned g_colkey[NROWS];
__device__ unsigned g_done;          // completion ticket (reset by prep)

__device__ __forceinline__ unsigned short f2bf_rne(float x){
    unsigned u = __float_as_uint(x);
    return (unsigned short)((u + 0x7FFFu + ((u >> 16) & 1u)) >> 16);
}
__device__ __forceinline__ float bf2f(unsigned short h){
    return __uint_as_float(((unsigned)h) << 16);
}
// monotone float -> uint key (order-preserving), so atomicMax works on floats
__device__ __forceinline__ unsigned fkey(float f){
    unsigned u = __float_as_uint(f);
    return (u & 0x80000000u) ? ~u : (u | 0x80000000u);
}
__device__ __forceinline__ float kinv(unsigned k){
    unsigned u = (k & 0x80000000u) ? (k ^ 0x80000000u) : ~k;
    return __uint_as_float(u);
}
__device__ __forceinline__ unsigned bytesum(unsigned w){
    return (w & 0xFFu) + ((w >> 8) & 0xFFu) + ((w >> 16) & 0xFFu) + (w >> 24);
}

__device__ __forceinline__ void load_lds16(const unsigned short* gptr, void* lptr){
    __builtin_amdgcn_global_load_lds(
        (const __attribute__((address_space(1))) unsigned int*)(uintptr_t)gptr,
        (__attribute__((address_space(3))) unsigned int*)(unsigned)(uintptr_t)lptr,
        16, 0, 0);
}

// One wave per row: fp32 diag dot, hi/lo bf16 split, unit-packed store (R18).
__global__ __launch_bounds__(256) void prep_kernel(const float* __restrict__ im,
                                                   const float* __restrict__ s){
    if (blockIdx.x == 0 && threadIdx.x == 0) g_done = 0u;   // ticket reset

    const int w    = threadIdx.x >> 6;
    const int lane = threadIdx.x & 63;
    const int row  = blockIdx.x * 4 + w;

    const float4 a = ((const float4*)(im + (size_t)row * DDIM))[lane];
    const float4 b = ((const float4*)(s  + (size_t)row * DDIM))[lane];

    float dp = a.x*b.x + a.y*b.y + a.z*b.z + a.w*b.w;
    #pragma unroll
    for (int m = 1; m < 64; m <<= 1) dp += __shfl_xor(dp, m, 64);
    if (lane == 0){
        g_diag[row]   = dp;
        g_rowcnt[row] = 0u; g_rowkey[row] = 0u;
        g_colcnt[row] = 0u; g_colkey[row] = 0u;
    }

    float av[4] = {a.x, a.y, a.z, a.w};
    float bv[4] = {b.x, b.y, b.z, b.w};
    unsigned short ah[4], al[4], bh[4], bl[4];
    #pragma unroll
    for (int i = 0; i < 4; ++i){
        ah[i] = f2bf_rne(av[i]); al[i] = f2bf_rne(av[i] - bf2f(ah[i]));
        bh[i] = f2bf_rne(bv[i]); bl[i] = f2bf_rne(bv[i] - bf2f(bh[i]));
    }
    const int blk = row >> 8, r = row & 255;
    const int kc  = lane >> 3;
    const int sp  = (((lane & 7) >> 1) ^ ((r >> 1) & 3));
    const int hf  = (lane & 1) * 4;
    const size_t ub = (size_t)blk * BLKSTRIDE + (size_t)(kc * 2) * 8192
                    + (size_t)r * 32 + sp * 8 + hf;      // hl=0 unit
    *(ushort4*)&gA[ub       ] = make_ushort4(ah[0], ah[1], ah[2], ah[3]);
    *(ushort4*)&gA[ub + 8192] = make_ushort4(al[0], al[1], al[2], al[3]);  // hl=1
    *(ushort4*)&gB[ub       ] = make_ushort4(bh[0], bh[1], bh[2], bh[3]);
    *(ushort4*)&gB[ub + 8192] = make_ushort4(bl[0], bl[1], bl[2], bl[3]);
}

// Stage one 16KB unit — pure sequential burst. 1024 threads: 1 DMA op each.
__device__ __forceinline__ void stage_unit256(const unsigned short* __restrict__ Obase,
                                              int c, int hl, unsigned short* sb, int tid){
    const unsigned short* u = Obase + (size_t)(c * 2 + hl) * 8192;
    load_lds16(u + (size_t)tid * 8, (char*)sb + tid * 16);
}

// ---- compute helpers (per-element math/order identical since R15) ----
#define MFQ4(A4, B4) { \
    _Pragma("unroll") \
    for (int i_ = 0; i_ < 4; ++i_){ \
        _Pragma("unroll") \
        for (int nj_ = 0; nj_ < 4; ++nj_) \
            acc[i_][nj_] = MFMA16((A4)[i_], (B4)[nj_], acc[i_][nj_], 0, 0, 0); \
    } }
#define LD4(U_, F_, OFF_) { \
    _Pragma("unroll") \
    for (int i_ = 0; i_ < 4; ++i_) \
        (F_)[i_] = *(const short8*)((const char*)(U_) + (OFF_) + i_ * 1024); }

// 256x256 tile, 16 waves (4Mx4N, 64x64/wave), 16x16x32 bf16, 3-pass hi/lo.
// R22 vs R21: K-loop + epilogue byte-identical; finalize FUSED via a
// last-block completion ticket (rocPRIM pattern): every block ends with
// threadfence -> syncthreads -> tid0 agent-scope fetch_add(g_done); the
// block seeing prev==1023 re-reads the stats arrays with agent-scope atomic
// loads (cross-XCD fresh) and runs the SAME 1024-thread double tree
// reduction the old finalize_kernel ran (same mapping => same bits).
// Removes one dispatch + gap + single-block cold-start latency.
__global__ __launch_bounds__(1024, 1) void gemm_stats_kernel(float* __restrict__ out){
    __shared__ unsigned short U[8][256 * 32];   // loop: staging; epilogue: partials; last block: red[]
    __shared__ float drow[256];
    __shared__ float dcol[256];
    __shared__ unsigned lastFlag;

    const int tid = threadIdx.x;
    const int bid = blockIdx.x;
    // bid[2:0]->XCD band of bi, bid[4:3]->bi within band, bid[9:5]->bj
    const int bi  = (bid & 7) * 4 + ((bid >> 3) & 3);
    const int bj  = bid >> 5;

    if (tid < 256)      drow[tid]       = g_diag[bi * 256 + tid];
    else if (tid < 512) dcol[tid - 256] = g_diag[bj * 256 + (tid - 256)];

    const int w    = tid >> 6, lane = tid & 63;
    const int quad = lane >> 4, l16 = lane & 15;
    const int wr   = w >> 2,   wc  = w & 3;                // 4x4 wave grid
    const int sel  = (quad ^ ((l16 >> 1) & 3)) << 4;       // swizzled 16B slot
    const int aoff = (wr * 64 + l16) * 64 + sel;           // byte off in A units
    const int boff = (wc * 64 + l16) * 64 + sel;           // byte off in B units

    floatx4 acc[4][4] = {};

    const unsigned short* Abase = gA + (size_t)bi * BLKSTRIDE;
    const unsigned short* Bbase = gB + (size_t)bj * BLKSTRIDE;

    // prologue: chunk 0's four units into buffer 0 (4 DMA ops/thread)
    stage_unit256(Abase, 0, 0, U[0], tid);
    stage_unit256(Bbase, 0, 0, U[2], tid);
    stage_unit256(Abase, 0, 1, U[4], tid);
    stage_unit256(Bbase, 0, 1, U[6], tid);

    // K-loop: 2 barriers/chunk; batch-issued next-chunk DMA; vmcnt(4)
    // retires chunk kc's 4 ops (issued a full chunk earlier); 3 compute
    // passes with compiler-scheduled ds_reads.
    #pragma unroll 1
    for (int kc = 0; kc < 8; ++kc){
        const int d = kc & 1, e = d ^ 1;

        __builtin_amdgcn_s_barrier();            // A: buf[e] readers done
        SBAR0();
        if (kc < 7){
            stage_unit256(Abase, kc + 1, 0, U[0 + e], tid);
            stage_unit256(Bbase, kc + 1, 0, U[2 + e], tid);
            stage_unit256(Abase, kc + 1, 1, U[4 + e], tid);
            stage_unit256(Bbase, kc + 1, 1, U[6 + e], tid);
            SBAR0();
            asm volatile("s_waitcnt vmcnt(4)" ::: "memory");   // chunk kc done
        } else {
            asm volatile("s_waitcnt vmcnt(0)" ::: "memory");   // tail drain
        }
        __builtin_amdgcn_s_barrier();            // B: publish chunk kc
        SBAR0();

        short8 ah[4], bh[4];
        LD4(U[0 + d], ah, aoff); LD4(U[2 + d], bh, boff);
        __builtin_amdgcn_s_setprio(1); MFQ4(ah, bh); __builtin_amdgcn_s_setprio(0);
        {
            short8 al[4]; LD4(U[4 + d], al, aoff);
            __builtin_amdgcn_s_setprio(1); MFQ4(al, bh); __builtin_amdgcn_s_setprio(0);
        }
        {
            short8 bl[4]; LD4(U[6 + d], bl, boff);
            __builtin_amdgcn_s_setprio(1); MFQ4(ah, bl); __builtin_amdgcn_s_setprio(0);
        }
    }

    // ================= stats epilogue (R19 scheme, 4x4 wave grid) =========
    __syncthreads();                 // all waves done reading U
    char* Lb = (char*)U;
    // layout in U (131072B): RMX f32[256][68] @0       (69,632B, 272B rows)
    //                        RCN u8 [256][72] @69,632  (18,432B)
    //                        CMX f32[256][20] @88,064  (20,480B, 80B rows)
    //                        CCN u8 [256][20] @108,544 (5,120B) -> end 113,664
    float*   RMX = (float*)Lb;
    uint8_t* RCN = (uint8_t*)(Lb + 69632);
    float*   CMX = (float*)(Lb + 88064);
    uint8_t* CCN = (uint8_t*)(Lb + 108544);

    const int c = wc * 16 + l16;     // row-partial slot [0,64)
    const int q = wr * 4 + quad;     // col-partial slot [0,16)

    // rows: fold 4 lane-local cols per (mi,r)  (16 rows/thread)
    #pragma unroll
    for (int mi = 0; mi < 4; ++mi){
        #pragma unroll
        for (int r = 0; r < 4; ++r){
            const int lrow = wr * 64 + mi * 16 + quad * 4 + r;
            const int gi   = bi * 256 + lrow;
            const float dv = drow[lrow];
            int cnt = 0; float mx = -3.0e38f;
            #pragma unroll
            for (int nj = 0; nj < 4; ++nj){
                const int gj  = bj * 256 + wc * 64 + nj * 16 + l16;
                const float v = acc[mi][nj][r];
                if (gi != gj){ cnt += (v < dv) ? 1 : 0; mx = fmaxf(mx, v); }
            }
            RMX[lrow * 68 + c] = mx;
            RCN[lrow * 72 + c] = (uint8_t)cnt;
        }
    }
    // cols: fold 16 lane-local rows per nj (4 cols/thread)
    #pragma unroll
    for (int nj = 0; nj < 4; ++nj){
        const int lcol = wc * 64 + nj * 16 + l16;
        const int gj   = bj * 256 + lcol;
        const float dv = dcol[lcol];
        int cnt = 0; float mx = -3.0e38f;
        #pragma unroll
        for (int mi = 0; mi < 4; ++mi){
            #pragma unroll
            for (int r = 0; r < 4; ++r){
                const int gi  = bi * 256 + wr * 64 + mi * 16 + quad * 4 + r;
                const float v = acc[mi][nj][r];
                if (gi != gj){ cnt += (v < dv) ? 1 : 0; mx = fmaxf(mx, v); }
            }
        }
        CMX[lcol * 20 + q] = mx;
        CCN[lcol * 20 + q] = (uint8_t)cnt;
    }
    __syncthreads();

    if (tid < 256){
        const int lrow = tid, gi = bi * 256 + lrow;
        const float4* rp = (const float4*)(Lb + (size_t)lrow * 272);
        float mx = -3.0e38f;
        #pragma unroll
        for (int k = 0; k < 16; ++k){
            const float4 v = rp[k];
            mx = fmaxf(mx, fmaxf(fmaxf(v.x, v.y), fmaxf(v.z, v.w)));
        }
        const uint2* cp = (const uint2*)(Lb + 69632 + (size_t)lrow * 72);
        unsigned cs = 0;
        #pragma unroll
        for (int k = 0; k < 8; ++k){
            const uint2 wv = cp[k];
            cs += bytesum(wv.x) + bytesum(wv.y);
        }
        atomicAdd(&g_rowcnt[gi], cs);
        atomicMax(&g_rowkey[gi], fkey(mx));
    } else if (tid < 512){
        const int lcol = tid - 256, gj = bj * 256 + lcol;
        const float4* qp = (const float4*)(Lb + 88064 + (size_t)lcol * 80);
        float mx = -3.0e38f;
        #pragma unroll
        for (int k = 0; k < 4; ++k){
            const float4 v = qp[k];
            mx = fmaxf(mx, fmaxf(fmaxf(v.x, v.y), fmaxf(v.z, v.w)));
        }
        const unsigned* cq = (const unsigned*)(Lb + 108544 + (size_t)lcol * 20);
        unsigned cs = 0;
        #pragma unroll
        for (int k = 0; k < 4; ++k) cs += bytesum(cq[k]);
        atomicAdd(&g_colcnt[gj], cs);
        atomicMax(&g_colkey[gj], fkey(mx));
    }

    // ================= fused finalize (last-block ticket) =================
    __threadfence();                 // this thread's atomics device-visible
    __syncthreads();                 // whole block's atomics fenced
    if (tid == 0){
        const unsigned prev = __hip_atomic_fetch_add(&g_done, 1u,
                                 __ATOMIC_ACQ_REL, __HIP_MEMORY_SCOPE_AGENT);
        lastFlag = (prev == 1023u) ? 1u : 0u;
    }
    __syncthreads();
    if (lastFlag){
        __threadfence();
        double* red = (double*)Lb;   // partials are dead; reuse LDS
        double a2 = 0.0;
        #pragma unroll
        for (int it = 0; it < NROWS / 1024; ++it){
            const int i = it * 1024 + tid;
            const float d   = g_diag[i];
            const unsigned rc = __hip_atomic_load(&g_rowcnt[i], __ATOMIC_RELAXED, __HIP_MEMORY_SCOPE_AGENT);
            const unsigned rk = __hip_atomic_load(&g_rowkey[i], __ATOMIC_RELAXED, __HIP_MEMORY_SCOPE_AGENT);
            const unsigned cc = __hip_atomic_load(&g_colcnt[i], __ATOMIC_RELAXED, __HIP_MEMORY_SCOPE_AGENT);
            const unsigned ck = __hip_atomic_load(&g_colkey[i], __ATOMIC_RELAXED, __HIP_MEMORY_SCOPE_AGENT);
            const float cs  = fmaxf(MARGIN_F + kinv(rk) - d, 0.0f) * (1.0f / (float)(rc + 1u));
            const float cim = fmaxf(MARGIN_F + kinv(ck) - d, 0.0f) * (1.0f / (float)(cc + 1u));
            a2 += (double)cs + (double)cim;
        }
        red[tid] = a2;
        __syncthreads();
        for (int s2 = 512; s2 > 0; s2 >>= 1){
            if (tid < s2) red[tid] += red[tid + s2];
            __syncthreads();
        }
        if (tid == 0) out[0] = (float)red[0];
    }
}

extern "C" void kernel_launch(void* const* d_in, const int* in_sizes, int n_in,
                              void* d_out, int out_size, void* d_ws, size_t ws_size,
                              hipStream_t stream){
    const float* im = (const float*)d_in[0];
    const float* s  = (const float*)d_in[1];
    float* out = (float*)d_out;

    prep_kernel<<<NROWS / 4, 256, 0, stream>>>(im, s);
    gemm_stats_kernel<<<1024, 1024, 0, stream>>>(out);
}

// Round 13
// 197.463 us; speedup vs baseline: 2.0814x; 2.0814x over previous
//
#include <hip/hip_runtime.h>
#include <stdint.h>

#define NROWS 8192
#define DDIM  256
#define K2    512          // hi|lo shorts per row (size bookkeeping only)
#define BLKSTRIDE 131072   // shorts per 256-row block (16 units x 8192)
#define MARGIN_F 0.2f
#define MFMA16 __builtin_amdgcn_mfma_f32_16x16x32_bf16
#define SBAR0() __builtin_amdgcn_sched_barrier(0)

typedef short  short8  __attribute__((ext_vector_type(8)));
typedef float  floatx4 __attribute__((ext_vector_type(4)));

// Unit-packed operand layout (R18, verified absmax 0): each 16KB staging unit
// (blk, kc, hl) is contiguous; slot swizzle baked in at pack time.
__device__ unsigned short gA[(size_t)NROWS * K2];   // im, unit-packed
__device__ unsigned short gB[(size_t)NROWS * K2];   // s,  unit-packed
__device__ float    g_diag[NROWS];
__device__ unsigned g_rowcnt[NROWS];
__device__ unsigned g_rowkey[NROWS];
__device__ unsigned g_colcnt[NROWS];
__device__ unsigned g_colkey[NROWS];

__device__ __forceinline__ unsigned short f2bf_rne(float x){
    unsigned u = __float_as_uint(x);
    return (unsigned short)((u + 0x7FFFu + ((u >> 16) & 1u)) >> 16);
}
__device__ __forceinline__ float bf2f(unsigned short h){
    return __uint_as_float(((unsigned)h) << 16);
}
// monotone float -> uint key (order-preserving), so atomicMax works on floats
__device__ __forceinline__ unsigned fkey(float f){
    unsigned u = __float_as_uint(f);
    return (u & 0x80000000u) ? ~u : (u | 0x80000000u);
}
__device__ __forceinline__ float kinv(unsigned k){
    unsigned u = (k & 0x80000000u) ? (k ^ 0x80000000u) : ~k;
    return __uint_as_float(u);
}
__device__ __forceinline__ unsigned bytesum(unsigned w){
    return (w & 0xFFu) + ((w >> 8) & 0xFFu) + ((w >> 16) & 0xFFu) + (w >> 24);
}

__device__ __forceinline__ void load_lds16(const unsigned short* gptr, void* lptr){
    __builtin_amdgcn_global_load_lds(
        (const __attribute__((address_space(1))) unsigned int*)(uintptr_t)gptr,
        (__attribute__((address_space(3))) unsigned int*)(unsigned)(uintptr_t)lptr,
        16, 0, 0);
}

// One wave per row: fp32 diag dot, hi/lo bf16 split, unit-packed store (R18).
__global__ __launch_bounds__(256) void prep_kernel(const float* __restrict__ im,
                                                   const float* __restrict__ s){
    const int w    = threadIdx.x >> 6;
    const int lane = threadIdx.x & 63;
    const int row  = blockIdx.x * 4 + w;

    const float4 a = ((const float4*)(im + (size_t)row * DDIM))[lane];
    const float4 b = ((const float4*)(s  + (size_t)row * DDIM))[lane];

    float dp = a.x*b.x + a.y*b.y + a.z*b.z + a.w*b.w;
    #pragma unroll
    for (int m = 1; m < 64; m <<= 1) dp += __shfl_xor(dp, m, 64);
    if (lane == 0){
        g_diag[row]   = dp;
        g_rowcnt[row] = 0u; g_rowkey[row] = 0u;
        g_colcnt[row] = 0u; g_colkey[row] = 0u;
    }

    float av[4] = {a.x, a.y, a.z, a.w};
    float bv[4] = {b.x, b.y, b.z, b.w};
    unsigned short ah[4], al[4], bh[4], bl[4];
    #pragma unroll
    for (int i = 0; i < 4; ++i){
        ah[i] = f2bf_rne(av[i]); al[i] = f2bf_rne(av[i] - bf2f(ah[i]));
        bh[i] = f2bf_rne(bv[i]); bl[i] = f2bf_rne(bv[i] - bf2f(bh[i]));
    }
    const int blk = row >> 8, r = row & 255;
    const int kc  = lane >> 3;
    const int sp  = (((lane & 7) >> 1) ^ ((r >> 1) & 3));
    const int hf  = (lane & 1) * 4;
    const size_t ub = (size_t)blk * BLKSTRIDE + (size_t)(kc * 2) * 8192
                    + (size_t)r * 32 + sp * 8 + hf;      // hl=0 unit
    *(ushort4*)&gA[ub       ] = make_ushort4(ah[0], ah[1], ah[2], ah[3]);
    *(ushort4*)&gA[ub + 8192] = make_ushort4(al[0], al[1], al[2], al[3]);  // hl=1
    *(ushort4*)&gB[ub       ] = make_ushort4(bh[0], bh[1], bh[2], bh[3]);
    *(ushort4*)&gB[ub + 8192] = make_ushort4(bl[0], bl[1], bl[2], bl[3]);
}

// Stage one 16KB unit — pure sequential burst. 1024 threads: 1 DMA op each.
__device__ __forceinline__ void stage_unit256(const unsigned short* __restrict__ Obase,
                                              int c, int hl, unsigned short* sb, int tid){
    const unsigned short* u = Obase + (size_t)(c * 2 + hl) * 8192;
    load_lds16(u + (size_t)tid * 8, (char*)sb + tid * 16);
}

// ---- compute helpers (per-element math/order identical since R15) ----
#define MFQ4(A4, B4) { \
    _Pragma("unroll") \
    for (int i_ = 0; i_ < 4; ++i_){ \
        _Pragma("unroll") \
        for (int nj_ = 0; nj_ < 4; ++nj_) \
            acc[i_][nj_] = MFMA16((A4)[i_], (B4)[nj_], acc[i_][nj_], 0, 0, 0); \
    } }
#define LD4(U_, F_, OFF_) { \
    _Pragma("unroll") \
    for (int i_ = 0; i_ < 4; ++i_) \
        (F_)[i_] = *(const short8*)((const char*)(U_) + (OFF_) + i_ * 1024); }

// 256x256 tile, 16 waves (4Mx4N, 64x64/wave), 16x16x32 bf16, 3-pass hi/lo.
// R23 vs R22: REVERT the fused finalize (R22 regressed 105->360us: per-block
// agent-scope ACQ_REL ticket + threadfence emit buffer_wbl2/buffer_inv ->
// ~1024 L2 invalidations during the dispatch -> co-resident blocks' staged
// reads fall to HBM latency. Lesson: no per-block device/agent fences on
// multi-XCD when siblings depend on L2). Separate 1024-thread finalize
// restored (R21 structure, 163.9us total).
// R23's one new lever: fragment PRELOAD. R21's chunk = ds_read ~3K cyc +
// MFMA ~3K cyc serialized (MfmaUtil 42% = MFMA/(MFMA+LDS)). Now ah/bh/al
// are issued before pass1 and bl right after pass1 starts -> pass2/3's LDS
// reads retire under pass1/2's MFMAs via counted lgkmcnt (DS completes
// in-order). Per-element accumulation order unchanged => absmax 0.
__global__ __launch_bounds__(1024, 1) void gemm_stats_kernel(){
    __shared__ unsigned short U[8][256 * 32];   // loop: staging; epilogue: partials
    __shared__ float drow[256];
    __shared__ float dcol[256];

    const int tid = threadIdx.x;
    const int bid = blockIdx.x;
    // bid[2:0]->XCD band of bi, bid[4:3]->bi within band, bid[9:5]->bj
    const int bi  = (bid & 7) * 4 + ((bid >> 3) & 3);
    const int bj  = bid >> 5;

    if (tid < 256)      drow[tid]       = g_diag[bi * 256 + tid];
    else if (tid < 512) dcol[tid - 256] = g_diag[bj * 256 + (tid - 256)];

    const int w    = tid >> 6, lane = tid & 63;
    const int quad = lane >> 4, l16 = lane & 15;
    const int wr   = w >> 2,   wc  = w & 3;                // 4x4 wave grid
    const int sel  = (quad ^ ((l16 >> 1) & 3)) << 4;       // swizzled 16B slot
    const int aoff = (wr * 64 + l16) * 64 + sel;           // byte off in A units
    const int boff = (wc * 64 + l16) * 64 + sel;           // byte off in B units

    floatx4 acc[4][4] = {};

    const unsigned short* Abase = gA + (size_t)bi * BLKSTRIDE;
    const unsigned short* Bbase = gB + (size_t)bj * BLKSTRIDE;

    // prologue: chunk 0's four units into buffer 0 (4 DMA ops/thread)
    stage_unit256(Abase, 0, 0, U[0], tid);
    stage_unit256(Bbase, 0, 0, U[2], tid);
    stage_unit256(Abase, 0, 1, U[4], tid);
    stage_unit256(Bbase, 0, 1, U[6], tid);

    // K-loop: 2 barriers/chunk; batch-issued next-chunk DMA; vmcnt(4)
    // retires chunk kc's 4 ops (issued a full chunk earlier); fragment
    // preload + 3 MFMA passes with compiler-counted lgkmcnt overlap.
    #pragma unroll 1
    for (int kc = 0; kc < 8; ++kc){
        const int d = kc & 1, e = d ^ 1;

        __builtin_amdgcn_s_barrier();            // A: buf[e] readers done
        SBAR0();
        if (kc < 7){
            stage_unit256(Abase, kc + 1, 0, U[0 + e], tid);
            stage_unit256(Bbase, kc + 1, 0, U[2 + e], tid);
            stage_unit256(Abase, kc + 1, 1, U[4 + e], tid);
            stage_unit256(Bbase, kc + 1, 1, U[6 + e], tid);
            SBAR0();
            asm volatile("s_waitcnt vmcnt(4)" ::: "memory");   // chunk kc done
        } else {
            asm volatile("s_waitcnt vmcnt(0)" ::: "memory");   // tail drain
        }
        __builtin_amdgcn_s_barrier();            // B: publish chunk kc
        SBAR0();

        // preload ah, bh, al (12 ds_read_b128 issued up-front)
        short8 ah[4], bh[4], al[4];
        LD4(U[0 + d], ah, aoff); LD4(U[2 + d], bh, boff); LD4(U[4 + d], al, aoff);
        __builtin_amdgcn_s_setprio(1); MFQ4(ah, bh); __builtin_amdgcn_s_setprio(0);
        // bl issued while pass1 MFMAs drain; retires under pass2
        short8 bl[4]; LD4(U[6 + d], bl, boff);
        __builtin_amdgcn_s_setprio(1); MFQ4(al, bh); __builtin_amdgcn_s_setprio(0);
        __builtin_amdgcn_s_setprio(1); MFQ4(ah, bl); __builtin_amdgcn_s_setprio(0);
    }

    // ================= stats epilogue (R19 scheme, 4x4 wave grid) =========
    __syncthreads();                 // all waves done reading U
    char* Lb = (char*)U;
    // layout in U (131072B): RMX f32[256][68] @0       (69,632B, 272B rows)
    //                        RCN u8 [256][72] @69,632  (18,432B)
    //                        CMX f32[256][20] @88,064  (20,480B, 80B rows)
    //                        CCN u8 [256][20] @108,544 (5,120B) -> end 113,664
    float*   RMX = (float*)Lb;
    uint8_t* RCN = (uint8_t*)(Lb + 69632);
    float*   CMX = (float*)(Lb + 88064);
    uint8_t* CCN = (uint8_t*)(Lb + 108544);

    const int c = wc * 16 + l16;     // row-partial slot [0,64)
    const int q = wr * 4 + quad;     // col-partial slot [0,16)

    // rows: fold 4 lane-local cols per (mi,r)  (16 rows/thread)
    #pragma unroll
    for (int mi = 0; mi < 4; ++mi){
        #pragma unroll
        for (int r = 0; r < 4; ++r){
            const int lrow = wr * 64 + mi * 16 + quad * 4 + r;
            const int gi   = bi * 256 + lrow;
            const float dv = drow[lrow];
            int cnt = 0; float mx = -3.0e38f;
            #pragma unroll
            for (int nj = 0; nj < 4; ++nj){
                const int gj  = bj * 256 + wc * 64 + nj * 16 + l16;
                const float v = acc[mi][nj][r];
                if (gi != gj){ cnt += (v < dv) ? 1 : 0; mx = fmaxf(mx, v); }
            }
            RMX[lrow * 68 + c] = mx;
            RCN[lrow * 72 + c] = (uint8_t)cnt;
        }
    }
    // cols: fold 16 lane-local rows per nj (4 cols/thread)
    #pragma unroll
    for (int nj = 0; nj < 4; ++nj){
        const int lcol = wc * 64 + nj * 16 + l16;
        const int gj   = bj * 256 + lcol;
        const float dv = dcol[lcol];
        int cnt = 0; float mx = -3.0e38f;
        #pragma unroll
        for (int mi = 0; mi < 4; ++mi){
            #pragma unroll
            for (int r = 0; r < 4; ++r){
                const int gi  = bi * 256 + wr * 64 + mi * 16 + quad * 4 + r;
                const float v = acc[mi][nj][r];
                if (gi != gj){ cnt += (v < dv) ? 1 : 0; mx = fmaxf(mx, v); }
            }
        }
        CMX[lcol * 20 + q] = mx;
        CCN[lcol * 20 + q] = (uint8_t)cnt;
    }
    __syncthreads();

    if (tid < 256){
        const int lrow = tid, gi = bi * 256 + lrow;
        const float4* rp = (const float4*)(Lb + (size_t)lrow * 272);
        float mx = -3.0e38f;
        #pragma unroll
        for (int k = 0; k < 16; ++k){
            const float4 v = rp[k];
            mx = fmaxf(mx, fmaxf(fmaxf(v.x, v.y), fmaxf(v.z, v.w)));
        }
        const uint2* cp = (const uint2*)(Lb + 69632 + (size_t)lrow * 72);
        unsigned cs = 0;
        #pragma unroll
        for (int k = 0; k < 8; ++k){
            const uint2 wv = cp[k];
            cs += bytesum(wv.x) + bytesum(wv.y);
        }
        atomicAdd(&g_rowcnt[gi], cs);
        atomicMax(&g_rowkey[gi], fkey(mx));
    } else if (tid < 512){
        const int lcol = tid - 256, gj = bj * 256 + lcol;
        const float4* qp = (const float4*)(Lb + 88064 + (size_t)lcol * 80);
        float mx = -3.0e38f;
        #pragma unroll
        for (int k = 0; k < 4; ++k){
            const float4 v = qp[k];
            mx = fmaxf(mx, fmaxf(fmaxf(v.x, v.y), fmaxf(v.z, v.w)));
        }
        const unsigned* cq = (const unsigned*)(Lb + 108544 + (size_t)lcol * 20);
        unsigned cs = 0;
        #pragma unroll
        for (int k = 0; k < 4; ++k) cs += bytesum(cq[k]);
        atomicAdd(&g_colcnt[gj], cs);
        atomicMax(&g_colkey[gj], fkey(mx));
    }
}

__global__ __launch_bounds__(1024) void finalize_kernel(float* __restrict__ out){
    __shared__ double red[1024];
    double acc = 0.0;
    #pragma unroll
    for (int it = 0; it < NROWS / 1024; ++it){
        const int i = it * 1024 + threadIdx.x;
        const float d  = g_diag[i];
        const float cs  = fmaxf(MARGIN_F + kinv(g_rowkey[i]) - d, 0.0f) * (1.0f / (float)(g_rowcnt[i] + 1u));
        const float cim = fmaxf(MARGIN_F + kinv(g_colkey[i]) - d, 0.0f) * (1.0f / (float)(g_colcnt[i] + 1u));
        acc += (double)cs + (double)cim;
    }
    red[threadIdx.x] = acc;
    __syncthreads();
    for (int s2 = 512; s2 > 0; s2 >>= 1){
        if (threadIdx.x < s2) red[threadIdx.x] += red[threadIdx.x + s2];
        __syncthreads();
    }
    if (threadIdx.x == 0) out[0] = (float)red[0];
}

extern "C" void kernel_launch(void* const* d_in, const int* in_sizes, int n_in,
                              void* d_out, int out_size, void* d_ws, size_t ws_size,
                              hipStream_t stream){
    const float* im = (const float*)d_in[0];
    const float* s  = (const float*)d_in[1];
    float* out = (float*)d_out;

    prep_kernel<<<NROWS / 4, 256, 0, stream>>>(im, s);
    gemm_stats_kernel<<<1024, 1024, 0, stream>>>();
    finalize_kernel<<<1, 1024, 0, stream>>>(out);
}

// Round 14
// 188.900 us; speedup vs baseline: 2.1758x; 1.0453x over previous
//
#include <hip/hip_runtime.h>
#include <stdint.h>

#define NROWS 8192
#define DDIM  256
#define K2    512          // hi|lo shorts per row (size bookkeeping only)
#define BLKSTRIDE 131072   // shorts per 256-row block (16 units x 8192)
#define MARGIN_F 0.2f
#define MFMA16 __builtin_amdgcn_mfma_f32_16x16x32_bf16
#define SBAR0() __builtin_amdgcn_sched_barrier(0)

typedef short  short8  __attribute__((ext_vector_type(8)));
typedef float  floatx4 __attribute__((ext_vector_type(4)));

// Unit-packed operand layout (R18, verified absmax 0): each 16KB staging unit
// (blk, kc, hl) is contiguous; slot swizzle baked in at pack time. An MFMA
// A-fragment row-block inside a unit is a CONTIGUOUS 1KB wave-burst -> A can
// be read directly from global (L1-resident) with perfect coalescing.
__device__ unsigned short gA[(size_t)NROWS * K2];   // im, unit-packed
__device__ unsigned short gB[(size_t)NROWS * K2];   // s,  unit-packed
__device__ float    g_diag[NROWS];
__device__ unsigned g_rowcnt[NROWS];
__device__ unsigned g_rowkey[NROWS];
__device__ unsigned g_colcnt[NROWS];
__device__ unsigned g_colkey[NROWS];

__device__ __forceinline__ unsigned short f2bf_rne(float x){
    unsigned u = __float_as_uint(x);
    return (unsigned short)((u + 0x7FFFu + ((u >> 16) & 1u)) >> 16);
}
__device__ __forceinline__ float bf2f(unsigned short h){
    return __uint_as_float(((unsigned)h) << 16);
}
// monotone float -> uint key (order-preserving), so atomicMax works on floats
__device__ __forceinline__ unsigned fkey(float f){
    unsigned u = __float_as_uint(f);
    return (u & 0x80000000u) ? ~u : (u | 0x80000000u);
}
__device__ __forceinline__ float kinv(unsigned k){
    unsigned u = (k & 0x80000000u) ? (k ^ 0x80000000u) : ~k;
    return __uint_as_float(u);
}
__device__ __forceinline__ unsigned bytesum(unsigned w){
    return (w & 0xFFu) + ((w >> 8) & 0xFFu) + ((w >> 16) & 0xFFu) + (w >> 24);
}

__device__ __forceinline__ void load_lds16(const unsigned short* gptr, void* lptr){
    __builtin_amdgcn_global_load_lds(
        (const __attribute__((address_space(1))) unsigned int*)(uintptr_t)gptr,
        (__attribute__((address_space(3))) unsigned int*)(unsigned)(uintptr_t)lptr,
        16, 0, 0);
}

// One wave per row: fp32 diag dot, hi/lo bf16 split, unit-packed store (R18).
__global__ __launch_bounds__(256) void prep_kernel(const float* __restrict__ im,
                                                   const float* __restrict__ s){
    const int w    = threadIdx.x >> 6;
    const int lane = threadIdx.x & 63;
    const int row  = blockIdx.x * 4 + w;

    const float4 a = ((const float4*)(im + (size_t)row * DDIM))[lane];
    const float4 b = ((const float4*)(s  + (size_t)row * DDIM))[lane];

    float dp = a.x*b.x + a.y*b.y + a.z*b.z + a.w*b.w;
    #pragma unroll
    for (int m = 1; m < 64; m <<= 1) dp += __shfl_xor(dp, m, 64);
    if (lane == 0){
        g_diag[row]   = dp;
        g_rowcnt[row] = 0u; g_rowkey[row] = 0u;
        g_colcnt[row] = 0u; g_colkey[row] = 0u;
    }

    float av[4] = {a.x, a.y, a.z, a.w};
    float bv[4] = {b.x, b.y, b.z, b.w};
    unsigned short ah[4], al[4], bh[4], bl[4];
    #pragma unroll
    for (int i = 0; i < 4; ++i){
        ah[i] = f2bf_rne(av[i]); al[i] = f2bf_rne(av[i] - bf2f(ah[i]));
        bh[i] = f2bf_rne(bv[i]); bl[i] = f2bf_rne(bv[i] - bf2f(bh[i]));
    }
    const int blk = row >> 8, r = row & 255;
    const int kc  = lane >> 3;
    const int sp  = (((lane & 7) >> 1) ^ ((r >> 1) & 3));
    const int hf  = (lane & 1) * 4;
    const size_t ub = (size_t)blk * BLKSTRIDE + (size_t)(kc * 2) * 8192
                    + (size_t)r * 32 + sp * 8 + hf;      // hl=0 unit
    *(ushort4*)&gA[ub       ] = make_ushort4(ah[0], ah[1], ah[2], ah[3]);
    *(ushort4*)&gA[ub + 8192] = make_ushort4(al[0], al[1], al[2], al[3]);  // hl=1
    *(ushort4*)&gB[ub       ] = make_ushort4(bh[0], bh[1], bh[2], bh[3]);
    *(ushort4*)&gB[ub + 8192] = make_ushort4(bl[0], bl[1], bl[2], bl[3]);
}

// Stage one 16KB unit — pure sequential burst. 1024 threads: 1 DMA op each.
__device__ __forceinline__ void stage_unit256(const unsigned short* __restrict__ Obase,
                                              int c, int hl, unsigned short* sb, int tid){
    const unsigned short* u = Obase + (size_t)(c * 2 + hl) * 8192;
    load_lds16(u + (size_t)tid * 8, (char*)sb + tid * 16);
}

// ---- compute helpers (per-element math/order identical since R15) ----
#define MFQ4(A4, B4) { \
    _Pragma("unroll") \
    for (int i_ = 0; i_ < 4; ++i_){ \
        _Pragma("unroll") \
        for (int nj_ = 0; nj_ < 4; ++nj_) \
            acc[i_][nj_] = MFMA16((A4)[i_], (B4)[nj_], acc[i_][nj_], 0, 0, 0); \
    } }
#define LD4(U_, F_, OFF_) { \
    _Pragma("unroll") \
    for (int i_ = 0; i_ < 4; ++i_) \
        (F_)[i_] = *(const short8*)((const char*)(U_) + (OFF_) + i_ * 1024); }
// A fragment from GLOBAL (unit-packed): same byte image as the LDS copy.
#define LDA4G(KC_, HL_, F_) { \
    const char* ab_ = (const char*)Abase + ((KC_) * 2 + (HL_)) * 16384 + aoff; \
    _Pragma("unroll") \
    for (int i_ = 0; i_ < 4; ++i_) \
        (F_)[i_] = *(const short8*)(ab_ + i_ * 1024); }

// 256x256 tile, 16 waves (4Mx4N, 64x64/wave), 16x16x32 bf16, 3-pass hi/lo.
// R24 vs R23: (1) REVERT the fragment preload — R23's 4 concurrent fragment
// arrays (64 VGPR on top of acc 64) spilled to scratch (WRITE_SIZE 4.6->97MB,
// the tripwire; gemm 105->138). Liveness budget = R21's 3-array/48-VGPR peak.
// (2) NEW: A read DIRECT from global (the unit-packed layout makes each
// A-fragment a contiguous 1KB wave-burst; chunk A-working-set 32KB = L1, 4x
// reuse across wc-waves). Loop ds_reads halve (16->8/wave), DMA halves
// (2 units/chunk). vmcnt ledger/thread: top issues 8 A-loads + 2 B-stages;
// vmcnt(2) retires B(kc)+A(kc), leaves B(kc+1); tail vmcnt(0). SBAR0 pins
// A-loads before stages so the 2 left in flight are exactly the B prefetch.
// Same values, same MFMA order => absmax 0.
__global__ __launch_bounds__(1024, 1) void gemm_stats_kernel(){
    __shared__ unsigned short U[8][256 * 32];   // loop: B staging (U[2+d],U[6+d]); epilogue: partials
    __shared__ float drow[256];
    __shared__ float dcol[256];

    const int tid = threadIdx.x;
    const int bid = blockIdx.x;
    // bid[2:0]->XCD band of bi, bid[4:3]->bi within band, bid[9:5]->bj
    const int bi  = (bid & 7) * 4 + ((bid >> 3) & 3);
    const int bj  = bid >> 5;

    if (tid < 256)      drow[tid]       = g_diag[bi * 256 + tid];
    else if (tid < 512) dcol[tid - 256] = g_diag[bj * 256 + (tid - 256)];

    const int w    = tid >> 6, lane = tid & 63;
    const int quad = lane >> 4, l16 = lane & 15;
    const int wr   = w >> 2,   wc  = w & 3;                // 4x4 wave grid
    const int sel  = (quad ^ ((l16 >> 1) & 3)) << 4;       // swizzled 16B slot
    const int aoff = (wr * 64 + l16) * 64 + sel;           // byte off in A units
    const int boff = (wc * 64 + l16) * 64 + sel;           // byte off in B units

    floatx4 acc[4][4] = {};

    const unsigned short* Abase = gA + (size_t)bi * BLKSTRIDE;
    const unsigned short* Bbase = gB + (size_t)bj * BLKSTRIDE;

    // prologue: chunk 0's B units into buffer 0 (2 DMA ops/thread)
    stage_unit256(Bbase, 0, 0, U[2], tid);
    stage_unit256(Bbase, 0, 1, U[6], tid);

    // K-loop: 2 barriers/chunk; A direct-from-global; B double-buffered in
    // LDS with batch-issued next-chunk DMA; counted vmcnt.
    #pragma unroll 1
    for (int kc = 0; kc < 8; ++kc){
        const int d = kc & 1, e = d ^ 1;

        __builtin_amdgcn_s_barrier();            // A: buf[e] readers done
        SBAR0();
        // this chunk's A fragments from global (8 x 1KB coalesced bursts)
        short8 ah[4], al[4];
        LDA4G(kc, 0, ah); LDA4G(kc, 1, al);
        SBAR0();                                 // pin: A-loads before stages
        if (kc < 7){
            stage_unit256(Bbase, kc + 1, 0, U[2 + e], tid);
            stage_unit256(Bbase, kc + 1, 1, U[6 + e], tid);
            SBAR0();
            asm volatile("s_waitcnt vmcnt(2)" ::: "memory");   // B(kc)+A(kc) done
        } else {
            asm volatile("s_waitcnt vmcnt(0)" ::: "memory");   // tail drain
        }
        __builtin_amdgcn_s_barrier();            // B: publish B(kc)
        SBAR0();

        short8 bh[4];
        LD4(U[2 + d], bh, boff);
        __builtin_amdgcn_s_setprio(1); MFQ4(ah, bh); __builtin_amdgcn_s_setprio(0);
        __builtin_amdgcn_s_setprio(1); MFQ4(al, bh); __builtin_amdgcn_s_setprio(0);
        {
            short8 bl[4]; LD4(U[6 + d], bl, boff);
            __builtin_amdgcn_s_setprio(1); MFQ4(ah, bl); __builtin_amdgcn_s_setprio(0);
        }
    }

    // ================= stats epilogue (R19 scheme, 4x4 wave grid) =========
    __syncthreads();                 // all waves done reading U
    char* Lb = (char*)U;
    // layout in U (131072B): RMX f32[256][68] @0       (69,632B, 272B rows)
    //                        RCN u8 [256][72] @69,632  (18,432B)
    //                        CMX f32[256][20] @88,064  (20,480B, 80B rows)
    //                        CCN u8 [256][20] @108,544 (5,120B) -> end 113,664
    float*   RMX = (float*)Lb;
    uint8_t* RCN = (uint8_t*)(Lb + 69632);
    float*   CMX = (float*)(Lb + 88064);
    uint8_t* CCN = (uint8_t*)(Lb + 108544);

    const int c = wc * 16 + l16;     // row-partial slot [0,64)
    const int q = wr * 4 + quad;     // col-partial slot [0,16)

    // rows: fold 4 lane-local cols per (mi,r)  (16 rows/thread)
    #pragma unroll
    for (int mi = 0; mi < 4; ++mi){
        #pragma unroll
        for (int r = 0; r < 4; ++r){
            const int lrow = wr * 64 + mi * 16 + quad * 4 + r;
            const int gi   = bi * 256 + lrow;
            const float dv = drow[lrow];
            int cnt = 0; float mx = -3.0e38f;
            #pragma unroll
            for (int nj = 0; nj < 4; ++nj){
                const int gj  = bj * 256 + wc * 64 + nj * 16 + l16;
                const float v = acc[mi][nj][r];
                if (gi != gj){ cnt += (v < dv) ? 1 : 0; mx = fmaxf(mx, v); }
            }
            RMX[lrow * 68 + c] = mx;
            RCN[lrow * 72 + c] = (uint8_t)cnt;
        }
    }
    // cols: fold 16 lane-local rows per nj (4 cols/thread)
    #pragma unroll
    for (int nj = 0; nj < 4; ++nj){
        const int lcol = wc * 64 + nj * 16 + l16;
        const int gj   = bj * 256 + lcol;
        const float dv = dcol[lcol];
        int cnt = 0; float mx = -3.0e38f;
        #pragma unroll
        for (int mi = 0; mi < 4; ++mi){
            #pragma unroll
            for (int r = 0; r < 4; ++r){
                const int gi  = bi * 256 + wr * 64 + mi * 16 + quad * 4 + r;
                const float v = acc[mi][nj][r];
                if (gi != gj){ cnt += (v < dv) ? 1 : 0; mx = fmaxf(mx, v); }
            }
        }
        CMX[lcol * 20 + q] = mx;
        CCN[lcol * 20 + q] = (uint8_t)cnt;
    }
    __syncthreads();

    if (tid < 256){
        const int lrow = tid, gi = bi * 256 + lrow;
        const float4* rp = (const float4*)(Lb + (size_t)lrow * 272);
        float mx = -3.0e38f;
        #pragma unroll
        for (int k = 0; k < 16; ++k){
            const float4 v = rp[k];
            mx = fmaxf(mx, fmaxf(fmaxf(v.x, v.y), fmaxf(v.z, v.w)));
        }
        const uint2* cp = (const uint2*)(Lb + 69632 + (size_t)lrow * 72);
        unsigned cs = 0;
        #pragma unroll
        for (int k = 0; k < 8; ++k){
            const uint2 wv = cp[k];
            cs += bytesum(wv.x) + bytesum(wv.y);
        }
        atomicAdd(&g_rowcnt[gi], cs);
        atomicMax(&g_rowkey[gi], fkey(mx));
    } else if (tid < 512){
        const int lcol = tid - 256, gj = bj * 256 + lcol;
        const float4* qp = (const float4*)(Lb + 88064 + (size_t)lcol * 80);
        float mx = -3.0e38f;
        #pragma unroll
        for (int k = 0; k < 4; ++k){
            const float4 v = qp[k];
            mx = fmaxf(mx, fmaxf(fmaxf(v.x, v.y), fmaxf(v.z, v.w)));
        }
        const unsigned* cq = (const unsigned*)(Lb + 108544 + (size_t)lcol * 20);
        unsigned cs = 0;
        #pragma unroll
        for (int k = 0; k < 4; ++k) cs += bytesum(cq[k]);
        atomicAdd(&g_colcnt[gj], cs);
        atomicMax(&g_colkey[gj], fkey(mx));
    }
}

__global__ __launch_bounds__(1024) void finalize_kernel(float* __restrict__ out){
    __shared__ double red[1024];
    double acc = 0.0;
    #pragma unroll
    for (int it = 0; it < NROWS / 1024; ++it){
        const int i = it * 1024 + threadIdx.x;
        const float d  = g_diag[i];
        const float cs  = fmaxf(MARGIN_F + kinv(g_rowkey[i]) - d, 0.0f) * (1.0f / (float)(g_rowcnt[i] + 1u));
        const float cim = fmaxf(MARGIN_F + kinv(g_colkey[i]) - d, 0.0f) * (1.0f / (float)(g_colcnt[i] + 1u));
        acc += (double)cs + (double)cim;
    }
    red[threadIdx.x] = acc;
    __syncthreads();
    for (int s2 = 512; s2 > 0; s2 >>= 1){
        if (threadIdx.x < s2) red[threadIdx.x] += red[threadIdx.x + s2];
        __syncthreads();
    }
    if (threadIdx.x == 0) out[0] = (float)red[0];
}

extern "C" void kernel_launch(void* const* d_in, const int* in_sizes, int n_in,
                              void* d_out, int out_size, void* d_ws, size_t ws_size,
                              hipStream_t stream){
    const float* im = (const float*)d_in[0];
    const float* s  = (const float*)d_in[1];
    float* out = (float*)d_out;

    prep_kernel<<<NROWS / 4, 256, 0, stream>>>(im, s);
    gemm_stats_kernel<<<1024, 1024, 0, stream>>>();
    finalize_kernel<<<1, 1024, 0, stream>>>(out);
}

// Round 15
// 157.170 us; speedup vs baseline: 2.6150x; 1.2019x over previous
//
#include <hip/hip_runtime.h>
#include <stdint.h>

#define NROWS 8192
#define DDIM  256
#define K2    512          // hi|lo shorts per row (size bookkeeping only)
#define BLKSTRIDE 131072   // shorts per 256-row block (16 units x 8192)
#define MARGIN_F 0.2f
#define MFMA16 __builtin_amdgcn_mfma_f32_16x16x32_bf16
#define SBAR0() __builtin_amdgcn_sched_barrier(0)

typedef short  short8  __attribute__((ext_vector_type(8)));
typedef float  floatx4 __attribute__((ext_vector_type(4)));

// Unit-packed operand layout (R18, verified absmax 0): each 16KB staging unit
// (blk, kc, hl) is contiguous; slot swizzle baked in at pack time.
__device__ unsigned short gA[(size_t)NROWS * K2];   // im, unit-packed
__device__ unsigned short gB[(size_t)NROWS * K2];   // s,  unit-packed
__device__ float    g_diag[NROWS];
__device__ unsigned g_rowcnt[NROWS];
__device__ unsigned g_rowkey[NROWS];
__device__ unsigned g_colcnt[NROWS];
__device__ unsigned g_colkey[NROWS];

__device__ __forceinline__ unsigned short f2bf_rne(float x){
    unsigned u = __float_as_uint(x);
    return (unsigned short)((u + 0x7FFFu + ((u >> 16) & 1u)) >> 16);
}
__device__ __forceinline__ float bf2f(unsigned short h){
    return __uint_as_float(((unsigned)h) << 16);
}
// monotone float -> uint key (order-preserving), so atomicMax works on floats
__device__ __forceinline__ unsigned fkey(float f){
    unsigned u = __float_as_uint(f);
    return (u & 0x80000000u) ? ~u : (u | 0x80000000u);
}
__device__ __forceinline__ float kinv(unsigned k){
    unsigned u = (k & 0x80000000u) ? (k ^ 0x80000000u) : ~k;
    return __uint_as_float(u);
}
__device__ __forceinline__ unsigned bytesum(unsigned w){
    return (w & 0xFFu) + ((w >> 8) & 0xFFu) + ((w >> 16) & 0xFFu) + (w >> 24);
}

__device__ __forceinline__ void load_lds16(const unsigned short* gptr, void* lptr){
    __builtin_amdgcn_global_load_lds(
        (const __attribute__((address_space(1))) unsigned int*)(uintptr_t)gptr,
        (__attribute__((address_space(3))) unsigned int*)(unsigned)(uintptr_t)lptr,
        16, 0, 0);
}

// One wave per row: fp32 diag dot, hi/lo bf16 split, unit-packed store (R18).
// UNTOUCHED since R18: the diag summation order feeds the absmax-0 chain.
__global__ __launch_bounds__(256) void prep_kernel(const float* __restrict__ im,
                                                   const float* __restrict__ s){
    const int w    = threadIdx.x >> 6;
    const int lane = threadIdx.x & 63;
    const int row  = blockIdx.x * 4 + w;

    const float4 a = ((const float4*)(im + (size_t)row * DDIM))[lane];
    const float4 b = ((const float4*)(s  + (size_t)row * DDIM))[lane];

    float dp = a.x*b.x + a.y*b.y + a.z*b.z + a.w*b.w;
    #pragma unroll
    for (int m = 1; m < 64; m <<= 1) dp += __shfl_xor(dp, m, 64);
    if (lane == 0){
        g_diag[row]   = dp;
        g_rowcnt[row] = 0u; g_rowkey[row] = 0u;
        g_colcnt[row] = 0u; g_colkey[row] = 0u;
    }

    float av[4] = {a.x, a.y, a.z, a.w};
    float bv[4] = {b.x, b.y, b.z, b.w};
    unsigned short ah[4], al[4], bh[4], bl[4];
    #pragma unroll
    for (int i = 0; i < 4; ++i){
        ah[i] = f2bf_rne(av[i]); al[i] = f2bf_rne(av[i] - bf2f(ah[i]));
        bh[i] = f2bf_rne(bv[i]); bl[i] = f2bf_rne(bv[i] - bf2f(bh[i]));
    }
    const int blk = row >> 8, r = row & 255;
    const int kc  = lane >> 3;
    const int sp  = (((lane & 7) >> 1) ^ ((r >> 1) & 3));
    const int hf  = (lane & 1) * 4;
    const size_t ub = (size_t)blk * BLKSTRIDE + (size_t)(kc * 2) * 8192
                    + (size_t)r * 32 + sp * 8 + hf;      // hl=0 unit
    *(ushort4*)&gA[ub       ] = make_ushort4(ah[0], ah[1], ah[2], ah[3]);
    *(ushort4*)&gA[ub + 8192] = make_ushort4(al[0], al[1], al[2], al[3]);  // hl=1
    *(ushort4*)&gB[ub       ] = make_ushort4(bh[0], bh[1], bh[2], bh[3]);
    *(ushort4*)&gB[ub + 8192] = make_ushort4(bl[0], bl[1], bl[2], bl[3]);
}

// Stage one 16KB unit — pure sequential burst. 1024 threads: 1 DMA op each.
__device__ __forceinline__ void stage_unit256(const unsigned short* __restrict__ Obase,
                                              int c, int hl, unsigned short* sb, int tid){
    const unsigned short* u = Obase + (size_t)(c * 2 + hl) * 8192;
    load_lds16(u + (size_t)tid * 8, (char*)sb + tid * 16);
}

// ---- compute helpers (per-element math/order identical since R15) ----
#define MFQ4(A4, B4) { \
    _Pragma("unroll") \
    for (int i_ = 0; i_ < 4; ++i_){ \
        _Pragma("unroll") \
        for (int nj_ = 0; nj_ < 4; ++nj_) \
            acc[i_][nj_] = MFMA16((A4)[i_], (B4)[nj_], acc[i_][nj_], 0, 0, 0); \
    } }
#define LD4(U_, F_, OFF_) { \
    _Pragma("unroll") \
    for (int i_ = 0; i_ < 4; ++i_) \
        (F_)[i_] = *(const short8*)((const char*)(U_) + (OFF_) + i_ * 1024); }

// 256x256 tile, 16 waves (4Mx4N, 64x64/wave), 16x16x32 bf16, 3-pass hi/lo.
// R25 vs R24: revert A-from-global (R24: 105->128us — vmcnt(2) waited the 8
// A-loads with zero compute cover; deeper A-prefetch would spill per R23).
// Back to R21 (session-best 105us gemm / 163.9 total) with ONE change:
// SINGLE barrier per chunk (was 2). Per chunk: stage S(kc+1) into buf e ->
// compute(d) -> vmcnt(0) [drains S(kc+1), issued a full compute-phase
// (~5K cyc) earlier -> near-free] -> barrier [publishes buf e AND licenses
// its overwrite: every wave's ds_reads are consumed (lgkmcnt) before it
// reaches the barrier]. 8 barriers/block instead of 16 -> 8 fewer full-CU
// lockstep re-alignment points for the LDS-burst/MFMA serialization.
// Per-element accumulation order unchanged => absmax 0.
__global__ __launch_bounds__(1024, 1) void gemm_stats_kernel(){
    __shared__ unsigned short U[8][256 * 32];   // loop: staging; epilogue: partials
    __shared__ float drow[256];
    __shared__ float dcol[256];

    const int tid = threadIdx.x;
    const int bid = blockIdx.x;
    // bid[2:0]->XCD band of bi, bid[4:3]->bi within band, bid[9:5]->bj
    const int bi  = (bid & 7) * 4 + ((bid >> 3) & 3);
    const int bj  = bid >> 5;

    if (tid < 256)      drow[tid]       = g_diag[bi * 256 + tid];
    else if (tid < 512) dcol[tid - 256] = g_diag[bj * 256 + (tid - 256)];

    const int w    = tid >> 6, lane = tid & 63;
    const int quad = lane >> 4, l16 = lane & 15;
    const int wr   = w >> 2,   wc  = w & 3;                // 4x4 wave grid
    const int sel  = (quad ^ ((l16 >> 1) & 3)) << 4;       // swizzled 16B slot
    const int aoff = (wr * 64 + l16) * 64 + sel;           // byte off in A units
    const int boff = (wc * 64 + l16) * 64 + sel;           // byte off in B units

    floatx4 acc[4][4] = {};

    const unsigned short* Abase = gA + (size_t)bi * BLKSTRIDE;
    const unsigned short* Bbase = gB + (size_t)bj * BLKSTRIDE;

    // prologue: chunk 0's four units into buffer 0 (4 DMA ops/thread)
    stage_unit256(Abase, 0, 0, U[0], tid);
    stage_unit256(Bbase, 0, 0, U[2], tid);
    stage_unit256(Abase, 0, 1, U[4], tid);
    stage_unit256(Bbase, 0, 1, U[6], tid);
    SBAR0();
    asm volatile("s_waitcnt vmcnt(0)" ::: "memory");
    __builtin_amdgcn_s_barrier();
    SBAR0();

    // K-loop: ONE barrier per chunk.
    #pragma unroll 1
    for (int kc = 0; kc < 8; ++kc){
        const int d = kc & 1, e = d ^ 1;

        if (kc < 7){
            // batch-issue next chunk into buf e (licensed by last barrier)
            stage_unit256(Abase, kc + 1, 0, U[0 + e], tid);
            stage_unit256(Bbase, kc + 1, 0, U[2 + e], tid);
            stage_unit256(Abase, kc + 1, 1, U[4 + e], tid);
            stage_unit256(Bbase, kc + 1, 1, U[6 + e], tid);
            SBAR0();
        }

        short8 ah[4], bh[4];
        LD4(U[0 + d], ah, aoff); LD4(U[2 + d], bh, boff);
        __builtin_amdgcn_s_setprio(1); MFQ4(ah, bh); __builtin_amdgcn_s_setprio(0);
        {
            short8 al[4]; LD4(U[4 + d], al, aoff);
            __builtin_amdgcn_s_setprio(1); MFQ4(al, bh); __builtin_amdgcn_s_setprio(0);
        }
        {
            short8 bl[4]; LD4(U[6 + d], bl, boff);
            __builtin_amdgcn_s_setprio(1); MFQ4(ah, bl); __builtin_amdgcn_s_setprio(0);
        }

        if (kc < 7){
            asm volatile("s_waitcnt vmcnt(0)" ::: "memory");   // S(kc+1) done (full-chunk cover)
            __builtin_amdgcn_s_barrier();                      // publish e + license d overwrite
            SBAR0();
        }
        // kc==7: epilogue's __syncthreads() covers the final ordering
    }

    // ================= stats epilogue (R19 scheme, 4x4 wave grid) =========
    __syncthreads();                 // all waves done reading U
    char* Lb = (char*)U;
    // layout in U (131072B): RMX f32[256][68] @0       (69,632B, 272B rows)
    //                        RCN u8 [256][72] @69,632  (18,432B)
    //                        CMX f32[256][20] @88,064  (20,480B, 80B rows)
    //                        CCN u8 [256][20] @108,544 (5,120B) -> end 113,664
    float*   RMX = (float*)Lb;
    uint8_t* RCN = (uint8_t*)(Lb + 69632);
    float*   CMX = (float*)(Lb + 88064);
    uint8_t* CCN = (uint8_t*)(Lb + 108544);

    const int c = wc * 16 + l16;     // row-partial slot [0,64)
    const int q = wr * 4 + quad;     // col-partial slot [0,16)

    // rows: fold 4 lane-local cols per (mi,r)  (16 rows/thread)
    #pragma unroll
    for (int mi = 0; mi < 4; ++mi){
        #pragma unroll
        for (int r = 0; r < 4; ++r){
            const int lrow = wr * 64 + mi * 16 + quad * 4 + r;
            const int gi   = bi * 256 + lrow;
            const float dv = drow[lrow];
            int cnt = 0; float mx = -3.0e38f;
            #pragma unroll
            for (int nj = 0; nj < 4; ++nj){
                const int gj  = bj * 256 + wc * 64 + nj * 16 + l16;
                const float v = acc[mi][nj][r];
                if (gi != gj){ cnt += (v < dv) ? 1 : 0; mx = fmaxf(mx, v); }
            }
            RMX[lrow * 68 + c] = mx;
            RCN[lrow * 72 + c] = (uint8_t)cnt;
        }
    }
    // cols: fold 16 lane-local rows per nj (4 cols/thread)
    #pragma unroll
    for (int nj = 0; nj < 4; ++nj){
        const int lcol = wc * 64 + nj * 16 + l16;
        const int gj   = bj * 256 + lcol;
        const float dv = dcol[lcol];
        int cnt = 0; float mx = -3.0e38f;
        #pragma unroll
        for (int mi = 0; mi < 4; ++mi){
            #pragma unroll
            for (int r = 0; r < 4; ++r){
                const int gi  = bi * 256 + wr * 64 + mi * 16 + quad * 4 + r;
                const float v = acc[mi][nj][r];
                if (gi != gj){ cnt += (v < dv) ? 1 : 0; mx = fmaxf(mx, v); }
            }
        }
        CMX[lcol * 20 + q] = mx;
        CCN[lcol * 20 + q] = (uint8_t)cnt;
    }
    __syncthreads();

    if (tid < 256){
        const int lrow = tid, gi = bi * 256 + lrow;
        const float4* rp = (const float4*)(Lb + (size_t)lrow * 272);
        float mx = -3.0e38f;
        #pragma unroll
        for (int k = 0; k < 16; ++k){
            const float4 v = rp[k];
            mx = fmaxf(mx, fmaxf(fmaxf(v.x, v.y), fmaxf(v.z, v.w)));
        }
        const uint2* cp = (const uint2*)(Lb + 69632 + (size_t)lrow * 72);
        unsigned cs = 0;
        #pragma unroll
        for (int k = 0; k < 8; ++k){
            const uint2 wv = cp[k];
            cs += bytesum(wv.x) + bytesum(wv.y);
        }
        atomicAdd(&g_rowcnt[gi], cs);
        atomicMax(&g_rowkey[gi], fkey(mx));
    } else if (tid < 512){
        const int lcol = tid - 256, gj = bj * 256 + lcol;
        const float4* qp = (const float4*)(Lb + 88064 + (size_t)lcol * 80);
        float mx = -3.0e38f;
        #pragma unroll
        for (int k = 0; k < 4; ++k){
            const float4 v = qp[k];
            mx = fmaxf(mx, fmaxf(fmaxf(v.x, v.y), fmaxf(v.z, v.w)));
        }
        const unsigned* cq = (const unsigned*)(Lb + 108544 + (size_t)lcol * 20);
        unsigned cs = 0;
        #pragma unroll
        for (int k = 0; k < 4; ++k) cs += bytesum(cq[k]);
        atomicAdd(&g_colcnt[gj], cs);
        atomicMax(&g_colkey[gj], fkey(mx));
    }
}

__global__ __launch_bounds__(1024) void finalize_kernel(float* __restrict__ out){
    __shared__ double red[1024];
    double acc = 0.0;
    #pragma unroll
    for (int it = 0; it < NROWS / 1024; ++it){
        const int i = it * 1024 + threadIdx.x;
        const float d  = g_diag[i];
        const float cs  = fmaxf(MARGIN_F + kinv(g_rowkey[i]) - d, 0.0f) * (1.0f / (float)(g_rowcnt[i] + 1u));
        const float cim = fmaxf(MARGIN_F + kinv(g_colkey[i]) - d, 0.0f) * (1.0f / (float)(g_colcnt[i] + 1u));
        acc += (double)cs + (double)cim;
    }
    red[threadIdx.x] = acc;
    __syncthreads();
    for (int s2 = 512; s2 > 0; s2 >>= 1){
        if (threadIdx.x < s2) red[threadIdx.x] += red[threadIdx.x + s2];
        __syncthreads();
    }
    if (threadIdx.x == 0) out[0] = (float)red[0];
}

extern "C" void kernel_launch(void* const* d_in, const int* in_sizes, int n_in,
                              void* d_out, int out_size, void* d_ws, size_t ws_size,
                              hipStream_t stream){
    const float* im = (const float*)d_in[0];
    const float* s  = (const float*)d_in[1];
    float* out = (float*)d_out;

    prep_kernel<<<NROWS / 4, 256, 0, stream>>>(im, s);
    gemm_stats_kernel<<<1024, 1024, 0, stream>>>();
    finalize_kernel<<<1, 1024, 0, stream>>>(out);
}